// Round 15
// baseline (131.264 us; speedup 1.0000x reference)
//
#include <hip/hip_runtime.h>

#define DEVINL __device__ __forceinline__

typedef __attribute__((ext_vector_type(4))) int i32x4;
typedef __attribute__((ext_vector_type(4))) float f32x4;
typedef __attribute__((ext_vector_type(8))) __bf16 bf16x8;

// exact-GELU via A&S 7.1.26 erf, lean form (~13 VALU + 2 trans):
// gelu(x) = 0.5x + 0.5|x| - (0.5|x|*p(t)) * 2^(-x^2 * log2e/2)
DEVINL float gelu_f(float x) {
  float ax = fabsf(x);
  float z = ax * 0.7071067811865476f;
  float t = __builtin_amdgcn_rcpf(fmaf(0.3275911f, z, 1.0f));
  float p = fmaf(1.061405429f, t, -1.453152027f);
  p = fmaf(p, t, 1.421413741f);
  p = fmaf(p, t, -0.284496736f);
  p = fmaf(p, t, 0.254829592f);
  p = p * t;
  float e = __builtin_amdgcn_exp2f(x * x * -0.7213475204444817f);
  float b = 0.5f * ax;
  float s = fmaf(0.5f, x, b);
  return fmaf(-(b * p), e, s);
}

DEVINL unsigned packq4(float a, float b, float c, float d, float scale) {
  int ia = (int)fminf(fmaxf(rintf(a * scale), -1.f), 1.f);
  int ib = (int)fminf(fmaxf(rintf(b * scale), -1.f), 1.f);
  int ic = (int)fminf(fmaxf(rintf(c * scale), -1.f), 1.f);
  int id = (int)fminf(fmaxf(rintf(d * scale), -1.f), 1.f);
  return (unsigned)(ia & 255) | ((unsigned)(ib & 255) << 8) |
         ((unsigned)(ic & 255) << 16) | ((unsigned)(id & 255) << 24);
}

// int8 quant: rndne -> med3 clamp -> cvt; byte-pack via 3 v_perm
DEVINL unsigned packq8(float a, float b, float c, float d, float s) {
  unsigned q0 = (unsigned)(int)__builtin_amdgcn_fmed3f(rintf(a * s), -128.f, 127.f);
  unsigned q1 = (unsigned)(int)__builtin_amdgcn_fmed3f(rintf(b * s), -128.f, 127.f);
  unsigned q2 = (unsigned)(int)__builtin_amdgcn_fmed3f(rintf(c * s), -128.f, 127.f);
  unsigned q3 = (unsigned)(int)__builtin_amdgcn_fmed3f(rintf(d * s), -128.f, 127.f);
  unsigned t0 = __builtin_amdgcn_perm(q1, q0, 0x00000400u);
  unsigned t1 = __builtin_amdgcn_perm(q3, q2, 0x00000400u);
  return __builtin_amdgcn_perm(t1, t0, 0x05040100u);
}

DEVINL long long mk64(unsigned lo, unsigned hi) {
  return (long long)(((unsigned long long)hi << 32) | (unsigned long long)lo);
}

// ------ kernel 0: ternary pack in MFMA-FRAG ORDER + pw bf16 hi/lo split -----
// (unchanged — layouts proven r6-r14)
__global__ __launch_bounds__(256) void k_prep(
    const float* __restrict__ w1, const float* __restrict__ w2,
    const float* __restrict__ pww, float* __restrict__ scales,
    unsigned* __restrict__ u1f, unsigned* __restrict__ u2f,
    unsigned short* __restrict__ pwbf) {
  const int tid = threadIdx.x;
  const int bx = blockIdx.x;

  if (bx == 2) {
    for (int e = tid; e < 4096; e += 256) {
      int n2 = e >> 10, kh = (e >> 9) & 1, ln = (e >> 3) & 63, j = e & 7;
      int c = ln & 15, hh = ln >> 4;
      float v = pww[(n2 * 16 + c) * 64 + kh * 32 + hh * 8 + j];
      __bf16 hb = (__bf16)v;
      __bf16 lb = (__bf16)(v - (float)hb);
      pwbf[e] = __builtin_bit_cast(unsigned short, hb);
      pwbf[e + 4096] = __builtin_bit_cast(unsigned short, lb);
    }
    return;
  }

  __shared__ double red[4];
  __shared__ float mclip_s;
  const float* w = (bx == 0) ? w1 : w2;

  double s = 0.0;
  for (int e = tid; e < 16384; e += 256) s += (double)fabsf(w[e]);
  #pragma unroll
  for (int m = 32; m; m >>= 1) s += __shfl_xor(s, m, 64);
  if ((tid & 63) == 0) red[tid >> 6] = s;
  __syncthreads();
  if (tid == 0) {
    double tot = red[0] + red[1] + red[2] + red[3];
    float mc = fmaxf((float)(tot / 16384.0), 1e-5f);
    scales[bx] = mc;
    mclip_s = mc;
  }
  __syncthreads();
  const float scale = 1.0f / mclip_s;

  if (bx == 0) {
    for (int e = tid; e < 4096; e += 256) {
      int n = e >> 8, lane = (e >> 2) & 63, word = e & 3;
      int r = n * 16 + (lane & 15);
      int kdw = (word >> 1) * 8 + (lane >> 4) * 2 + (word & 1);
      const float* src = w1 + (r * 16 + kdw) * 4;
      u1f[e] = packq4(src[0], src[1], src[2], src[3], scale);
    }
  } else {
    for (int e = tid; e < 4096; e += 256) {
      int ks = e >> 9, n2 = (e >> 7) & 3, lane = (e >> 1) & 63, word = e & 1;
      int r = n2 * 16 + (lane & 15);
      int kdw = ks * 8 + (lane >> 4) * 2 + word;
      const float* src = w2 + (r * 64 + kdw) * 4;
      u2f[e] = packq4(src[0], src[1], src[2], src[3], scale);
    }
  }
}

// ---- kernel 1: depthwise 3x3, 4 outputs/thread, packed {bf16hi,bf16lo} ----
// (unchanged from r8; at its ~21 us HBM floor)
__global__ __launch_bounds__(256, 8) void k_dw(
    const float* __restrict__ x, const float* __restrict__ dww,
    const float* __restrict__ dwb, unsigned* __restrict__ hout) {
  const int tid = threadIdx.x;
  const int px = tid & 127, yq = tid >> 7;
  const int y0 = (blockIdx.x * 2 + yq) * 4;
  const int c = blockIdx.y, bz = blockIdx.z;
  const float* xc = x + (((size_t)bz * 64 + c) << 14);

  float wv[9];
  #pragma unroll
  for (int i = 0; i < 9; ++i) wv[i] = dww[c * 9 + i];
  const float bias = dwb[c];

  float v[6][3];
  #pragma unroll
  for (int ry = 0; ry < 6; ++ry) {
    int iy = y0 - 1 + ry;
    bool yok = (unsigned)iy < 128u;
    const float* row = xc + ((size_t)(iy & 127) << 7);
    #pragma unroll
    for (int dx = 0; dx < 3; ++dx) {
      int ix = px - 1 + dx;
      v[ry][dx] = (yok && (unsigned)ix < 128u) ? row[ix & 127] : 0.f;
    }
  }

  unsigned* op = hout + (((size_t)bz * 64 + c) << 14) + ((size_t)y0 << 7) + px;
  #pragma unroll
  for (int oy = 0; oy < 4; ++oy) {
    float acc = bias;
    #pragma unroll
    for (int ky = 0; ky < 3; ++ky)
      #pragma unroll
      for (int kx = 0; kx < 3; ++kx)
        acc = fmaf(v[oy + ky][kx], wv[ky * 3 + kx], acc);
    __bf16 hb = (__bf16)acc;
    __bf16 lb = (__bf16)(acc - (float)hb);
    op[(size_t)oy << 7] =
        ((unsigned)__builtin_bit_cast(unsigned short, hb) << 16) |
        (unsigned)__builtin_bit_cast(unsigned short, lb);
  }
}

// ------ kernel 2: cooperative-wave pw + LN + BitFF + residual ---------------
// r14 body + SOFTWARE-PIPELINED h loads: uc[] is preloaded for it=0; inside
// the loop, uc is consumed by the byte-perms, then the loads for it+1 are
// reissued into uc immediately — the whole iteration's compute then covers
// the vmcnt latency (the ~25% idle seen in r14 counters).
// __launch_bounds__(256,4) is the proven rung (r12/r13: higher spills).
__global__ __launch_bounds__(256, 4) void k_fused(
    const float* __restrict__ pwb, const float* __restrict__ lnw,
    const float* __restrict__ lnb, const float* __restrict__ b1,
    const float* __restrict__ b2, const float* __restrict__ scales,
    const unsigned* __restrict__ u1f, const unsigned* __restrict__ u2f,
    const uint4* __restrict__ pwf, const unsigned* hpk, float* dout) {
  __shared__ __align__(16) unsigned wq[16 * 18];   // [tok][18 dw] int8 x
  __shared__ __align__(16) unsigned qf2[16 * 70];  // [tok][70 dw] int8 gelu
  __shared__ float redA[2][4][16], redB[2][4][16];

  const int tid = threadIdx.x;
  const int w = tid >> 6, lane = tid & 63;
  const int col = lane & 15, hi = lane >> 4;
  const int y = blockIdx.x, bz = blockIdx.y;
  const size_t gbase = ((size_t)bz * 64) << 14;

  // ---- prefetch h for it=0 (issued before everything else) ----
  unsigned uc[2][8];
  {
    const int g0 = y * 128 + col;
    #pragma unroll
    for (int kh = 0; kh < 2; ++kh)
      #pragma unroll
      for (int j = 0; j < 8; ++j)
        uc[kh][j] = hpk[gbase + (((size_t)(kh * 32 + hi * 8 + j)) << 14) + g0];
  }

  // ---- per-lane params (channel ch = w*16 + 4*hi + r) ----
  const int chb = w * 16 + 4 * hi;
  float pwbr[4], lnw_r[4], lnb_r[4], b2r[4];
  #pragma unroll
  for (int r = 0; r < 4; ++r) {
    pwbr[r] = pwb[chb + r];
    lnw_r[r] = lnw[chb + r];
    lnb_r[r] = lnb[chb + r];
    b2r[r] = b2[chb + r];
  }
  float4 b1r[4];
  #pragma unroll
  for (int n = 0; n < 4; ++n)
    b1r[n] = *(const float4*)&b1[w * 64 + n * 16 + 4 * hi];
  const float sc0 = scales[0], m2c = scales[1];

  // ---- ALL weight fragments -> registers ----
  uint4 pwa[2], pwl[2];
  #pragma unroll
  for (int kh = 0; kh < 2; ++kh) {
    pwa[kh] = pwf[(w * 2 + kh) * 64 + lane];
    pwl[kh] = pwf[(w * 2 + kh) * 64 + lane + 512];
  }
  uint4 w1r[4];
  #pragma unroll
  for (int n = 0; n < 4; ++n)
    w1r[n] = *(const uint4*)&u1f[(((w * 4 + n) * 64) + lane) * 4];
  uint2 w2r[8];
  #pragma unroll
  for (int ks = 0; ks < 8; ++ks)
    w2r[ks] = *(const uint2*)&u2f[(((ks * 4 + w) * 64) + lane) * 2];

  #pragma unroll 1
  for (int it = 0; it < 8; ++it) {
    const int gcol = y * 128 + it * 16 + col;

    // ---- consume prefetched h: build bf16 B-frags via byte-perm ----
    bf16x8 bh[2], bl[2];
    #pragma unroll
    for (int kh = 0; kh < 2; ++kh) {
      uint4 bhw, blw;
      #pragma unroll
      for (int jw = 0; jw < 4; ++jw) {
        ((unsigned*)&bhw)[jw] =
            __builtin_amdgcn_perm(uc[kh][2 * jw + 1], uc[kh][2 * jw], 0x07060302u);
        ((unsigned*)&blw)[jw] =
            __builtin_amdgcn_perm(uc[kh][2 * jw + 1], uc[kh][2 * jw], 0x05040100u);
      }
      bh[kh] = __builtin_bit_cast(bf16x8, bhw);
      bl[kh] = __builtin_bit_cast(bf16x8, blw);
    }

    // ---- issue h loads for it+1 (latency hidden under this iteration) ----
    if (it < 7) {
      const int gn = gcol + 16;
      #pragma unroll
      for (int kh = 0; kh < 2; ++kh)
        #pragma unroll
        for (int j = 0; j < 8; ++j)
          uc[kh][j] =
              hpk[gbase + (((size_t)(kh * 32 + hi * 8 + j)) << 14) + gn];
    }

    // ---- pw GEMM slice (bf16 hi/lo 3-term), out ch w*16+4hi+r ----
    f32x4 pacc = {0.f, 0.f, 0.f, 0.f};
    #pragma unroll
    for (int kh = 0; kh < 2; ++kh) {
      bf16x8 ah = __builtin_bit_cast(bf16x8, pwa[kh]);
      bf16x8 al = __builtin_bit_cast(bf16x8, pwl[kh]);
      pacc = __builtin_amdgcn_mfma_f32_16x16x32_bf16(ah, bh[kh], pacc, 0, 0, 0);
      pacc = __builtin_amdgcn_mfma_f32_16x16x32_bf16(ah, bl[kh], pacc, 0, 0, 0);
      pacc = __builtin_amdgcn_mfma_f32_16x16x32_bf16(al, bh[kh], pacc, 0, 0, 0);
    }
    float hacc[4];
    #pragma unroll
    for (int r = 0; r < 4; ++r) hacc[r] = pacc[r] + pwbr[r];

    // ---- S1: LN mean/var partials -> wave -> block ----
    float s1 = 0.f, q1 = 0.f;
    #pragma unroll
    for (int r = 0; r < 4; ++r) {
      s1 += hacc[r];
      q1 = fmaf(hacc[r], hacc[r], q1);
    }
    s1 += __shfl_xor(s1, 16, 64); s1 += __shfl_xor(s1, 32, 64);
    q1 += __shfl_xor(q1, 16, 64); q1 += __shfl_xor(q1, 32, 64);
    if (hi == 0) { redA[0][w][col] = s1; redB[0][w][col] = q1; }
    __syncthreads();  // B1
    float S = redA[0][0][col] + redA[0][1][col] + redA[0][2][col] + redA[0][3][col];
    float Q = redB[0][0][col] + redB[0][1][col] + redB[0][2][col] + redB[0][3][col];
    const float mu = S * (1.f / 64.f);
    const float var = fmaxf(Q * (1.f / 64.f) - mu * mu, 0.f);
    const float istd = __builtin_amdgcn_rsqf(var + 1e-5f);

    // ---- tn + S2: rms1/amax partials ----
    float tn[4];
    float s2 = 0.f, am = 0.f;
    #pragma unroll
    for (int r = 0; r < 4; ++r) {
      float t = (hacc[r] - mu) * istd * lnw_r[r] + lnb_r[r];
      tn[r] = t;
      s2 = fmaf(t, t, s2);
      am = fmaxf(am, fabsf(t));
    }
    s2 += __shfl_xor(s2, 16, 64); s2 += __shfl_xor(s2, 32, 64);
    am = fmaxf(am, __shfl_xor(am, 16, 64));
    am = fmaxf(am, __shfl_xor(am, 32, 64));
    if (hi == 0) { redA[1][w][col] = s2; redB[1][w][col] = am; }
    __syncthreads();  // B2
    float S2 = redA[1][0][col] + redA[1][1][col] + redA[1][2][col] + redA[1][3][col];
    float AM = fmaxf(fmaxf(redB[1][0][col], redB[1][1][col]),
                     fmaxf(redB[1][2][col], redB[1][3][col]));

    // inv1 = 1/max(sqrt(S2),1e-12) == rsq(max(S2,1e-24)) (guarded, 1 trans)
    const float inv1 = __builtin_amdgcn_rsqf(fmaxf(S2, 1e-24f));
    const float axc1 = fmaxf(AM * 8.f * inv1, 1e-5f);
    const float sx1 = 127.f * __builtin_amdgcn_rcpf(axc1);
    const float qs1 = 8.f * inv1 * sx1;
    const float fsc1 = sc0 * axc1 * (1.f / 127.f);

    // ---- quantize x slice -> shared wq (stride 18, conflict-free) ----
    wq[col * 18 + w * 4 + hi] = packq8(tn[0], tn[1], tn[2], tn[3], qs1);
    __syncthreads();  // B3

    // ---- BitLinear1: features w*64..+63, interleaved dequant+GELU ----
    const uint2 bw0 = *(const uint2*)&wq[col * 18 + 2 * hi];
    const uint2 bw1 = *(const uint2*)&wq[col * 18 + 8 + 2 * hi];
    const long long bq0 = mk64(bw0.x, bw0.y);
    const long long bq1 = mk64(bw1.x, bw1.y);

    float g[4][4];
    float sum2 = 0.f, am2 = 0.f;
    #pragma unroll
    for (int n = 0; n < 4; ++n) {
      i32x4 cc = {0, 0, 0, 0};
      cc = __builtin_amdgcn_mfma_i32_16x16x32_i8(mk64(w1r[n].x, w1r[n].y), bq0,
                                                 cc, 0, 0, 0);
      cc = __builtin_amdgcn_mfma_i32_16x16x32_i8(mk64(w1r[n].z, w1r[n].w), bq1,
                                                 cc, 0, 0, 0);
      #pragma unroll
      for (int r = 0; r < 4; ++r) {
        float f = (float)cc[r] * fsc1 + ((const float*)&b1r[n])[r];
        float gg = gelu_f(f);
        g[n][r] = gg;
        sum2 = fmaf(gg, gg, sum2);
        am2 = fmaxf(am2, fabsf(gg));
      }
    }
    sum2 += __shfl_xor(sum2, 16, 64); sum2 += __shfl_xor(sum2, 32, 64);
    am2 = fmaxf(am2, __shfl_xor(am2, 16, 64));
    am2 = fmaxf(am2, __shfl_xor(am2, 32, 64));
    if (hi == 0) { redA[0][w][col] = sum2; redB[0][w][col] = am2; }
    __syncthreads();  // B4
    float S4 = redA[0][0][col] + redA[0][1][col] + redA[0][2][col] + redA[0][3][col];
    float AM2 = fmaxf(fmaxf(redB[0][0][col], redB[0][1][col]),
                      fmaxf(redB[0][2][col], redB[0][3][col]));

    const float inv2 = __builtin_amdgcn_rsqf(fmaxf(S4, 1e-24f));
    const float axc2 = fmaxf(AM2 * 16.f * inv2, 1e-5f);
    const float sx2 = 127.f * __builtin_amdgcn_rcpf(axc2);
    const float qs2 = 16.f * inv2 * sx2;
    const float fsc2 = m2c * axc2 * (1.f / 127.f);

    // ---- quantize gelu slice -> shared qf2 (stride 70, conflict-free) ----
    #pragma unroll
    for (int n = 0; n < 4; ++n)
      qf2[col * 70 + w * 16 + n * 4 + hi] =
          packq8(g[n][0], g[n][1], g[n][2], g[n][3], qs2);
    __syncthreads();  // B5

    // ---- BitLinear2: out ch w*16..+15, K=256 in 8 k-steps ----
    i32x4 c2 = {0, 0, 0, 0};
    #pragma unroll
    for (int ks = 0; ks < 8; ++ks) {
      const uint2 bw = *(const uint2*)&qf2[col * 70 + ks * 8 + 2 * hi];
      const long long bfr = mk64(bw.x, bw.y);
      const long long afr = mk64(w2r[ks].x, w2r[ks].y);
      c2 = __builtin_amdgcn_mfma_i32_16x16x32_i8(afr, bfr, c2, 0, 0, 0);
    }

    // ---- epilogue: dequant + b2 + residual (regs), store ----
    #pragma unroll
    for (int r = 0; r < 4; ++r) {
      float v = (float)c2[r] * fsc2 + b2r[r] + hacc[r];
      dout[gbase + (((size_t)(chb + r)) << 14) + gcol] = v;
    }
  }
}

extern "C" void kernel_launch(void* const* d_in, const int* in_sizes, int n_in,
                              void* d_out, int out_size, void* d_ws, size_t ws_size,
                              hipStream_t stream) {
  (void)in_sizes; (void)n_in; (void)out_size; (void)ws_size;
  const float* x   = (const float*)d_in[0];
  const float* dww = (const float*)d_in[1];
  const float* dwb = (const float*)d_in[2];
  const float* pww = (const float*)d_in[3];
  const float* pwb = (const float*)d_in[4];
  const float* lnw = (const float*)d_in[5];
  const float* lnb = (const float*)d_in[6];
  const float* w1  = (const float*)d_in[7];
  const float* b1  = (const float*)d_in[8];
  const float* w2  = (const float*)d_in[9];
  const float* b2  = (const float*)d_in[10];
  float* out = (float*)d_out;

  float* scales = (float*)d_ws;
  unsigned* u1f = (unsigned*)((char*)d_ws + 16);
  unsigned* u2f = u1f + 4096;
  unsigned short* pwbf = (unsigned short*)((char*)d_ws + 16 + 32768);

  hipLaunchKernelGGL(k_prep, dim3(3), dim3(256), 0, stream,
                     w1, w2, pww, scales, u1f, u2f, pwbf);
  hipLaunchKernelGGL(k_dw, dim3(16, 64, 16), dim3(256), 0, stream,
                     x, dww, dwb, (unsigned*)out);
  hipLaunchKernelGGL(k_fused, dim3(128, 16), dim3(256), 0, stream,
                     pwb, lnw, lnb, b1, b2, scales, u1f, u2f,
                     (const uint4*)pwbf, (const unsigned*)out, out);
}

// Round 16
// 119.838 us; speedup vs baseline: 1.0954x; 1.0954x over previous
//
#include <hip/hip_runtime.h>

#define DEVINL __device__ __forceinline__

typedef __attribute__((ext_vector_type(4))) int i32x4;
typedef __attribute__((ext_vector_type(4))) float f32x4;
typedef __attribute__((ext_vector_type(8))) __bf16 bf16x8;

// exact-GELU via A&S 7.1.26 erf, lean form (~13 VALU + 2 trans):
// gelu(x) = 0.5x + 0.5|x| - (0.5|x|*p(t)) * 2^(-x^2 * log2e/2)
DEVINL float gelu_f(float x) {
  float ax = fabsf(x);
  float z = ax * 0.7071067811865476f;
  float t = __builtin_amdgcn_rcpf(fmaf(0.3275911f, z, 1.0f));
  float p = fmaf(1.061405429f, t, -1.453152027f);
  p = fmaf(p, t, 1.421413741f);
  p = fmaf(p, t, -0.284496736f);
  p = fmaf(p, t, 0.254829592f);
  p = p * t;
  float e = __builtin_amdgcn_exp2f(x * x * -0.7213475204444817f);
  float b = 0.5f * ax;
  float s = fmaf(0.5f, x, b);
  return fmaf(-(b * p), e, s);
}

DEVINL unsigned packq4(float a, float b, float c, float d, float scale) {
  int ia = (int)fminf(fmaxf(rintf(a * scale), -1.f), 1.f);
  int ib = (int)fminf(fmaxf(rintf(b * scale), -1.f), 1.f);
  int ic = (int)fminf(fmaxf(rintf(c * scale), -1.f), 1.f);
  int id = (int)fminf(fmaxf(rintf(d * scale), -1.f), 1.f);
  return (unsigned)(ia & 255) | ((unsigned)(ib & 255) << 8) |
         ((unsigned)(ic & 255) << 16) | ((unsigned)(id & 255) << 24);
}

// int8 quant: rndne -> med3 clamp -> cvt; byte-pack via 3 v_perm
DEVINL unsigned packq8(float a, float b, float c, float d, float s) {
  unsigned q0 = (unsigned)(int)__builtin_amdgcn_fmed3f(rintf(a * s), -128.f, 127.f);
  unsigned q1 = (unsigned)(int)__builtin_amdgcn_fmed3f(rintf(b * s), -128.f, 127.f);
  unsigned q2 = (unsigned)(int)__builtin_amdgcn_fmed3f(rintf(c * s), -128.f, 127.f);
  unsigned q3 = (unsigned)(int)__builtin_amdgcn_fmed3f(rintf(d * s), -128.f, 127.f);
  unsigned t0 = __builtin_amdgcn_perm(q1, q0, 0x00000400u);
  unsigned t1 = __builtin_amdgcn_perm(q3, q2, 0x00000400u);
  return __builtin_amdgcn_perm(t1, t0, 0x05040100u);
}

DEVINL long long mk64(unsigned lo, unsigned hi) {
  return (long long)(((unsigned long long)hi << 32) | (unsigned long long)lo);
}

// ------ kernel 0: ternary pack in MFMA-FRAG ORDER + pw bf16 hi/lo split -----
// (unchanged — layouts proven r6-r15)
__global__ __launch_bounds__(256) void k_prep(
    const float* __restrict__ w1, const float* __restrict__ w2,
    const float* __restrict__ pww, float* __restrict__ scales,
    unsigned* __restrict__ u1f, unsigned* __restrict__ u2f,
    unsigned short* __restrict__ pwbf) {
  const int tid = threadIdx.x;
  const int bx = blockIdx.x;

  if (bx == 2) {
    for (int e = tid; e < 4096; e += 256) {
      int n2 = e >> 10, kh = (e >> 9) & 1, ln = (e >> 3) & 63, j = e & 7;
      int c = ln & 15, hh = ln >> 4;
      float v = pww[(n2 * 16 + c) * 64 + kh * 32 + hh * 8 + j];
      __bf16 hb = (__bf16)v;
      __bf16 lb = (__bf16)(v - (float)hb);
      pwbf[e] = __builtin_bit_cast(unsigned short, hb);
      pwbf[e + 4096] = __builtin_bit_cast(unsigned short, lb);
    }
    return;
  }

  __shared__ double red[4];
  __shared__ float mclip_s;
  const float* w = (bx == 0) ? w1 : w2;

  double s = 0.0;
  for (int e = tid; e < 16384; e += 256) s += (double)fabsf(w[e]);
  #pragma unroll
  for (int m = 32; m; m >>= 1) s += __shfl_xor(s, m, 64);
  if ((tid & 63) == 0) red[tid >> 6] = s;
  __syncthreads();
  if (tid == 0) {
    double tot = red[0] + red[1] + red[2] + red[3];
    float mc = fmaxf((float)(tot / 16384.0), 1e-5f);
    scales[bx] = mc;
    mclip_s = mc;
  }
  __syncthreads();
  const float scale = 1.0f / mclip_s;

  if (bx == 0) {
    for (int e = tid; e < 4096; e += 256) {
      int n = e >> 8, lane = (e >> 2) & 63, word = e & 3;
      int r = n * 16 + (lane & 15);
      int kdw = (word >> 1) * 8 + (lane >> 4) * 2 + (word & 1);
      const float* src = w1 + (r * 16 + kdw) * 4;
      u1f[e] = packq4(src[0], src[1], src[2], src[3], scale);
    }
  } else {
    for (int e = tid; e < 4096; e += 256) {
      int ks = e >> 9, n2 = (e >> 7) & 3, lane = (e >> 1) & 63, word = e & 1;
      int r = n2 * 16 + (lane & 15);
      int kdw = ks * 8 + (lane >> 4) * 2 + word;
      const float* src = w2 + (r * 64 + kdw) * 4;
      u2f[e] = packq4(src[0], src[1], src[2], src[3], scale);
    }
  }
}

// ---- kernel 1: depthwise 3x3, 4 outputs/thread, packed {bf16hi,bf16lo} ----
// (unchanged from r8; at its ~21 us HBM floor)
__global__ __launch_bounds__(256, 8) void k_dw(
    const float* __restrict__ x, const float* __restrict__ dww,
    const float* __restrict__ dwb, unsigned* __restrict__ hout) {
  const int tid = threadIdx.x;
  const int px = tid & 127, yq = tid >> 7;
  const int y0 = (blockIdx.x * 2 + yq) * 4;
  const int c = blockIdx.y, bz = blockIdx.z;
  const float* xc = x + (((size_t)bz * 64 + c) << 14);

  float wv[9];
  #pragma unroll
  for (int i = 0; i < 9; ++i) wv[i] = dww[c * 9 + i];
  const float bias = dwb[c];

  float v[6][3];
  #pragma unroll
  for (int ry = 0; ry < 6; ++ry) {
    int iy = y0 - 1 + ry;
    bool yok = (unsigned)iy < 128u;
    const float* row = xc + ((size_t)(iy & 127) << 7);
    #pragma unroll
    for (int dx = 0; dx < 3; ++dx) {
      int ix = px - 1 + dx;
      v[ry][dx] = (yok && (unsigned)ix < 128u) ? row[ix & 127] : 0.f;
    }
  }

  unsigned* op = hout + (((size_t)bz * 64 + c) << 14) + ((size_t)y0 << 7) + px;
  #pragma unroll
  for (int oy = 0; oy < 4; ++oy) {
    float acc = bias;
    #pragma unroll
    for (int ky = 0; ky < 3; ++ky)
      #pragma unroll
      for (int kx = 0; kx < 3; ++kx)
        acc = fmaf(v[oy + ky][kx], wv[ky * 3 + kx], acc);
    __bf16 hb = (__bf16)acc;
    __bf16 lb = (__bf16)(acc - (float)hb);
    op[(size_t)oy << 7] =
        ((unsigned)__builtin_bit_cast(unsigned short, hb) << 16) |
        (unsigned)__builtin_bit_cast(unsigned short, lb);
  }
}

// ------ kernel 2: cooperative-wave pw + LN + BitFF + residual ---------------
// r14 body with params/biases staged in LDS (not registers): static reg
// demand drops from ~110 to ~78 in the 64-reg budget (arch budget = 256/waves
// — r12/r13/r15 evidence), so the compiler stops re-loading weights from
// global each iteration. Weights stay in registers. Numerics identical.
__global__ __launch_bounds__(256, 4) void k_fused(
    const float* __restrict__ pwb, const float* __restrict__ lnw,
    const float* __restrict__ lnb, const float* __restrict__ b1,
    const float* __restrict__ b2, const float* __restrict__ scales,
    const unsigned* __restrict__ u1f, const unsigned* __restrict__ u2f,
    const uint4* __restrict__ pwf, const unsigned* hpk, float* dout) {
  __shared__ __align__(16) unsigned wq[16 * 18];   // [tok][18 dw] int8 x
  __shared__ __align__(16) unsigned qf2[16 * 70];  // [tok][70 dw] int8 gelu
  __shared__ float redA[2][4][16], redB[2][4][16];
  __shared__ __align__(16) float b1s[256];
  __shared__ __align__(16) float pwb_s[64], lnw_s[64], lnb_s[64], b2s[64];

  const int tid = threadIdx.x;
  const int w = tid >> 6, lane = tid & 63;
  const int col = lane & 15, hi = lane >> 4;
  const int y = blockIdx.x, bz = blockIdx.y;
  const size_t gbase = ((size_t)bz * 64) << 14;
  const int chb = w * 16 + 4 * hi;

  // ---- stage params/biases in LDS (frees ~32 regs of static demand) ----
  b1s[tid] = b1[tid];
  if (tid < 64) {
    pwb_s[tid] = pwb[tid];
    lnw_s[tid] = lnw[tid];
    lnb_s[tid] = lnb[tid];
    b2s[tid] = b2[tid];
  }
  const float sc0 = scales[0], m2c = scales[1];

  // ---- ALL weight fragments -> registers ----
  uint4 pwa[2], pwl[2];
  #pragma unroll
  for (int kh = 0; kh < 2; ++kh) {
    pwa[kh] = pwf[(w * 2 + kh) * 64 + lane];
    pwl[kh] = pwf[(w * 2 + kh) * 64 + lane + 512];
  }
  uint4 w1r[4];
  #pragma unroll
  for (int n = 0; n < 4; ++n)
    w1r[n] = *(const uint4*)&u1f[(((w * 4 + n) * 64) + lane) * 4];
  uint2 w2r[8];
  #pragma unroll
  for (int ks = 0; ks < 8; ++ks)
    w2r[ks] = *(const uint2*)&u2f[(((ks * 4 + w) * 64) + lane) * 2];

  __syncthreads();  // params staged (covers pwb_s use in iter 0)

  #pragma unroll 1
  for (int it = 0; it < 8; ++it) {
    const int gcol = y * 128 + it * 16 + col;

    // ---- load packed h, build bf16 B-frags via byte-perm ----
    bf16x8 bh[2], bl[2];
    #pragma unroll
    for (int kh = 0; kh < 2; ++kh) {
      unsigned u[8];
      #pragma unroll
      for (int j = 0; j < 8; ++j)
        u[j] = hpk[gbase + (((size_t)(kh * 32 + hi * 8 + j)) << 14) + gcol];
      uint4 bhw, blw;
      #pragma unroll
      for (int jw = 0; jw < 4; ++jw) {
        ((unsigned*)&bhw)[jw] =
            __builtin_amdgcn_perm(u[2 * jw + 1], u[2 * jw], 0x07060302u);
        ((unsigned*)&blw)[jw] =
            __builtin_amdgcn_perm(u[2 * jw + 1], u[2 * jw], 0x05040100u);
      }
      bh[kh] = __builtin_bit_cast(bf16x8, bhw);
      bl[kh] = __builtin_bit_cast(bf16x8, blw);
    }

    // ---- pw GEMM slice (bf16 hi/lo 3-term), out ch w*16+4hi+r ----
    f32x4 pacc = {0.f, 0.f, 0.f, 0.f};
    #pragma unroll
    for (int kh = 0; kh < 2; ++kh) {
      bf16x8 ah = __builtin_bit_cast(bf16x8, pwa[kh]);
      bf16x8 al = __builtin_bit_cast(bf16x8, pwl[kh]);
      pacc = __builtin_amdgcn_mfma_f32_16x16x32_bf16(ah, bh[kh], pacc, 0, 0, 0);
      pacc = __builtin_amdgcn_mfma_f32_16x16x32_bf16(ah, bl[kh], pacc, 0, 0, 0);
      pacc = __builtin_amdgcn_mfma_f32_16x16x32_bf16(al, bh[kh], pacc, 0, 0, 0);
    }
    float hacc[4];
    {
      const float4 pb = *(const float4*)&pwb_s[chb];
      #pragma unroll
      for (int r = 0; r < 4; ++r) hacc[r] = pacc[r] + ((const float*)&pb)[r];
    }

    // ---- S1: LN mean/var partials -> wave -> block ----
    float s1 = 0.f, q1 = 0.f;
    #pragma unroll
    for (int r = 0; r < 4; ++r) {
      s1 += hacc[r];
      q1 = fmaf(hacc[r], hacc[r], q1);
    }
    s1 += __shfl_xor(s1, 16, 64); s1 += __shfl_xor(s1, 32, 64);
    q1 += __shfl_xor(q1, 16, 64); q1 += __shfl_xor(q1, 32, 64);
    if (hi == 0) { redA[0][w][col] = s1; redB[0][w][col] = q1; }
    __syncthreads();  // B1
    float S = redA[0][0][col] + redA[0][1][col] + redA[0][2][col] + redA[0][3][col];
    float Q = redB[0][0][col] + redB[0][1][col] + redB[0][2][col] + redB[0][3][col];
    const float mu = S * (1.f / 64.f);
    const float var = fmaxf(Q * (1.f / 64.f) - mu * mu, 0.f);
    const float istd = __builtin_amdgcn_rsqf(var + 1e-5f);

    // ---- tn + S2: rms1/amax partials ----
    float tn[4];
    float s2 = 0.f, am = 0.f;
    {
      const float4 lw = *(const float4*)&lnw_s[chb];
      const float4 lb = *(const float4*)&lnb_s[chb];
      #pragma unroll
      for (int r = 0; r < 4; ++r) {
        float t = (hacc[r] - mu) * istd * ((const float*)&lw)[r] +
                  ((const float*)&lb)[r];
        tn[r] = t;
        s2 = fmaf(t, t, s2);
        am = fmaxf(am, fabsf(t));
      }
    }
    s2 += __shfl_xor(s2, 16, 64); s2 += __shfl_xor(s2, 32, 64);
    am = fmaxf(am, __shfl_xor(am, 16, 64));
    am = fmaxf(am, __shfl_xor(am, 32, 64));
    if (hi == 0) { redA[1][w][col] = s2; redB[1][w][col] = am; }
    __syncthreads();  // B2
    float S2 = redA[1][0][col] + redA[1][1][col] + redA[1][2][col] + redA[1][3][col];
    float AM = fmaxf(fmaxf(redB[1][0][col], redB[1][1][col]),
                     fmaxf(redB[1][2][col], redB[1][3][col]));

    // inv1 = 1/max(sqrt(S2),1e-12) == rsq(max(S2,1e-24)) (guarded, 1 trans)
    const float inv1 = __builtin_amdgcn_rsqf(fmaxf(S2, 1e-24f));
    const float axc1 = fmaxf(AM * 8.f * inv1, 1e-5f);
    const float sx1 = 127.f * __builtin_amdgcn_rcpf(axc1);
    const float qs1 = 8.f * inv1 * sx1;
    const float fsc1 = sc0 * axc1 * (1.f / 127.f);

    // ---- quantize x slice -> shared wq (stride 18, conflict-free) ----
    wq[col * 18 + w * 4 + hi] = packq8(tn[0], tn[1], tn[2], tn[3], qs1);
    __syncthreads();  // B3

    // ---- BitLinear1: features w*64..+63, interleaved dequant+GELU ----
    const uint2 bw0 = *(const uint2*)&wq[col * 18 + 2 * hi];
    const uint2 bw1 = *(const uint2*)&wq[col * 18 + 8 + 2 * hi];
    const long long bq0 = mk64(bw0.x, bw0.y);
    const long long bq1 = mk64(bw1.x, bw1.y);

    float g[4][4];
    float sum2 = 0.f, am2 = 0.f;
    #pragma unroll
    for (int n = 0; n < 4; ++n) {
      i32x4 cc = {0, 0, 0, 0};
      cc = __builtin_amdgcn_mfma_i32_16x16x32_i8(mk64(w1r[n].x, w1r[n].y), bq0,
                                                 cc, 0, 0, 0);
      cc = __builtin_amdgcn_mfma_i32_16x16x32_i8(mk64(w1r[n].z, w1r[n].w), bq1,
                                                 cc, 0, 0, 0);
      const float4 bb = *(const float4*)&b1s[w * 64 + n * 16 + 4 * hi];
      #pragma unroll
      for (int r = 0; r < 4; ++r) {
        float f = (float)cc[r] * fsc1 + ((const float*)&bb)[r];
        float gg = gelu_f(f);
        g[n][r] = gg;
        sum2 = fmaf(gg, gg, sum2);
        am2 = fmaxf(am2, fabsf(gg));
      }
    }
    sum2 += __shfl_xor(sum2, 16, 64); sum2 += __shfl_xor(sum2, 32, 64);
    am2 = fmaxf(am2, __shfl_xor(am2, 16, 64));
    am2 = fmaxf(am2, __shfl_xor(am2, 32, 64));
    if (hi == 0) { redA[0][w][col] = sum2; redB[0][w][col] = am2; }
    __syncthreads();  // B4
    float S4 = redA[0][0][col] + redA[0][1][col] + redA[0][2][col] + redA[0][3][col];
    float AM2 = fmaxf(fmaxf(redB[0][0][col], redB[0][1][col]),
                      fmaxf(redB[0][2][col], redB[0][3][col]));

    const float inv2 = __builtin_amdgcn_rsqf(fmaxf(S4, 1e-24f));
    const float axc2 = fmaxf(AM2 * 16.f * inv2, 1e-5f);
    const float sx2 = 127.f * __builtin_amdgcn_rcpf(axc2);
    const float qs2 = 16.f * inv2 * sx2;
    const float fsc2 = m2c * axc2 * (1.f / 127.f);

    // ---- quantize gelu slice -> shared qf2 (stride 70, conflict-free) ----
    #pragma unroll
    for (int n = 0; n < 4; ++n)
      qf2[col * 70 + w * 16 + n * 4 + hi] =
          packq8(g[n][0], g[n][1], g[n][2], g[n][3], qs2);
    __syncthreads();  // B5

    // ---- BitLinear2: out ch w*16..+15, K=256 in 8 k-steps ----
    i32x4 c2 = {0, 0, 0, 0};
    #pragma unroll
    for (int ks = 0; ks < 8; ++ks) {
      const uint2 bw = *(const uint2*)&qf2[col * 70 + ks * 8 + 2 * hi];
      const long long bfr = mk64(bw.x, bw.y);
      const long long afr = mk64(w2r[ks].x, w2r[ks].y);
      c2 = __builtin_amdgcn_mfma_i32_16x16x32_i8(afr, bfr, c2, 0, 0, 0);
    }

    // ---- epilogue: dequant + b2 + residual (regs), store ----
    {
      const float4 bb2 = *(const float4*)&b2s[chb];
      #pragma unroll
      for (int r = 0; r < 4; ++r) {
        float v = (float)c2[r] * fsc2 + ((const float*)&bb2)[r] + hacc[r];
        dout[gbase + (((size_t)(chb + r)) << 14) + gcol] = v;
      }
    }
  }
}

extern "C" void kernel_launch(void* const* d_in, const int* in_sizes, int n_in,
                              void* d_out, int out_size, void* d_ws, size_t ws_size,
                              hipStream_t stream) {
  (void)in_sizes; (void)n_in; (void)out_size; (void)ws_size;
  const float* x   = (const float*)d_in[0];
  const float* dww = (const float*)d_in[1];
  const float* dwb = (const float*)d_in[2];
  const float* pww = (const float*)d_in[3];
  const float* pwb = (const float*)d_in[4];
  const float* lnw = (const float*)d_in[5];
  const float* lnb = (const float*)d_in[6];
  const float* w1  = (const float*)d_in[7];
  const float* b1  = (const float*)d_in[8];
  const float* w2  = (const float*)d_in[9];
  const float* b2  = (const float*)d_in[10];
  float* out = (float*)d_out;

  float* scales = (float*)d_ws;
  unsigned* u1f = (unsigned*)((char*)d_ws + 16);
  unsigned* u2f = u1f + 4096;
  unsigned short* pwbf = (unsigned short*)((char*)d_ws + 16 + 32768);

  hipLaunchKernelGGL(k_prep, dim3(3), dim3(256), 0, stream,
                     w1, w2, pww, scales, u1f, u2f, pwbf);
  hipLaunchKernelGGL(k_dw, dim3(16, 64, 16), dim3(256), 0, stream,
                     x, dww, dwb, (unsigned*)out);
  hipLaunchKernelGGL(k_fused, dim3(128, 16), dim3(256), 0, stream,
                     pwb, lnw, lnb, b1, b2, scales, u1f, u2f,
                     (const uint4*)pwbf, (const unsigned*)out, out);
}